// Round 1
// baseline (210.394 us; speedup 1.0000x reference)
//
#include <hip/hip_runtime.h>
#include <hip/hip_bf16.h>

#define CODE_DIM 256
#define HIDDEN   128
#define HEADS    4
#define N_CODES  100000
#define N_SPEC   256

#define K2_BLOCKS 256
#define K2_TPB    512
#define K2_WPB    (K2_TPB / 64)            // waves per block = 8
#define K2_TOTAL_WAVES (K2_BLOCKS * K2_WPB) // 2048

// workspace layout (floats):
//   [0, 1024)                  v[h][d]        (h*256 + d)
//   [1024, 1028)               c[h]
//   [1028, 1028 + 256*1028)    per-block partials: s_un[4][256] ++ dsum[4]
#define WS_V 0
#define WS_C 1024
#define WS_PART 1028
#define PART_STRIDE (HEADS * CODE_DIM + HEADS)  // 1028

// K1: v[h,d] = dot(W[h,d,:], a2[h]);  c[h] = sum_d pe[d]*dot(W[h,d,:],a1[h]) + b.a1 + b.a2
__global__ void k1_prep(const float* __restrict__ pe, const float* __restrict__ W,
                        const float* __restrict__ b, const float* __restrict__ a,
                        float* __restrict__ ws) {
    const int h = blockIdx.x;       // 4 blocks, one per head
    const int d = threadIdx.x;      // 256 threads, one per input dim
    __shared__ float a_sh[2 * HIDDEN];    // a[h][:] : a1 = [0,128), a2 = [128,256)
    a_sh[d] = a[h * 2 * HIDDEN + d];
    __syncthreads();

    const float4* wr4 = (const float4*)(W + ((size_t)h * CODE_DIM + d) * HIDDEN);
    float u = 0.f, v = 0.f;
#pragma unroll
    for (int kk = 0; kk < HIDDEN / 4; ++kk) {
        float4 wv = wr4[kk];
        int k = 4 * kk;
        u += wv.x * a_sh[k]            + wv.y * a_sh[k + 1]
           + wv.z * a_sh[k + 2]        + wv.w * a_sh[k + 3];
        v += wv.x * a_sh[HIDDEN + k]     + wv.y * a_sh[HIDDEN + k + 1]
           + wv.z * a_sh[HIDDEN + k + 2] + wv.w * a_sh[HIDDEN + k + 3];
    }
    ws[WS_V + h * CODE_DIM + d] = v;

    float red = pe[d] * u;
    if (d < HIDDEN) red += b[h * HIDDEN + d] * (a_sh[d] + a_sh[HIDDEN + d]); // b.a1 + b.a2
#pragma unroll
    for (int off = 32; off; off >>= 1) red += __shfl_xor(red, off, 64);
    __shared__ float wsum[4];
    if ((threadIdx.x & 63) == 0) wsum[threadIdx.x >> 6] = red;
    __syncthreads();
    if (threadIdx.x == 0) ws[WS_C + h] = wsum[0] + wsum[1] + wsum[2] + wsum[3];
}

// K2: one pass over code_embs. Wave-per-row; un-normalized online softmax accumulation.
__global__ __launch_bounds__(K2_TPB) void k2_main(const float* __restrict__ code,
                                                  const float* __restrict__ ws_ro,
                                                  float* __restrict__ part) {
    const int lane = threadIdx.x & 63;
    const int w    = threadIdx.x >> 6;
    const int wg   = blockIdx.x * K2_WPB + w;   // global wave id [0, 2048)

    float4 vh[HEADS];
    float  ch[HEADS];
#pragma unroll
    for (int h = 0; h < HEADS; ++h) {
        vh[h] = ((const float4*)(ws_ro + WS_V + h * CODE_DIM))[lane];
        ch[h] = ws_ro[WS_C + h];
    }
    float4 acc[HEADS];
    float  dsum[HEADS];
#pragma unroll
    for (int h = 0; h < HEADS; ++h) {
        acc[h] = make_float4(0.f, 0.f, 0.f, 0.f);
        dsum[h] = 0.f;
    }

    const int S = K2_TOTAL_WAVES;
    int n0 = wg;
    float4 x0 = make_float4(0.f, 0.f, 0.f, 0.f);
    float4 x1 = make_float4(0.f, 0.f, 0.f, 0.f);
    if (n0 < N_CODES)     x0 = ((const float4*)(code + (size_t)n0 * CODE_DIM))[lane];
    if (n0 + S < N_CODES) x1 = ((const float4*)(code + (size_t)(n0 + S) * CODE_DIM))[lane];

    for (int n = n0; n < N_CODES; n += S) {
        // prefetch depth-2
        float4 x2 = make_float4(0.f, 0.f, 0.f, 0.f);
        if (n + 2 * S < N_CODES)
            x2 = ((const float4*)(code + (size_t)(n + 2 * S) * CODE_DIM))[lane];

        float p[HEADS];
#pragma unroll
        for (int h = 0; h < HEADS; ++h)
            p[h] = x0.x * vh[h].x + x0.y * vh[h].y + x0.z * vh[h].z + x0.w * vh[h].w;
#pragma unroll
        for (int off = 32; off; off >>= 1) {
            p[0] += __shfl_xor(p[0], off, 64);
            p[1] += __shfl_xor(p[1], off, 64);
            p[2] += __shfl_xor(p[2], off, 64);
            p[3] += __shfl_xor(p[3], off, 64);
        }
#pragma unroll
        for (int h = 0; h < HEADS; ++h) {
            float e = p[h] + ch[h];
            e = (e >= 0.f) ? e : 0.2f * e;       // leaky relu
            float t = __expf(e);                 // un-normalized softmax weight
            dsum[h] += t;
            acc[h].x += t * x0.x; acc[h].y += t * x0.y;
            acc[h].z += t * x0.z; acc[h].w += t * x0.w;
        }
        x0 = x1; x1 = x2;
    }

    // block-level reduction of 8 wave accumulators -> per-block partial
    __shared__ float red[K2_WPB][HEADS * CODE_DIM];  // 32 KB
    __shared__ float redd[K2_WPB][HEADS];
#pragma unroll
    for (int h = 0; h < HEADS; ++h)
        ((float4*)(&red[w][h * CODE_DIM]))[lane] = acc[h];
    if (lane == 0) {
#pragma unroll
        for (int h = 0; h < HEADS; ++h) redd[w][h] = dsum[h];
    }
    __syncthreads();

    float* outp = part + (size_t)blockIdx.x * PART_STRIDE;
    for (int o = threadIdx.x; o < HEADS * CODE_DIM; o += K2_TPB) {
        float s = 0.f;
#pragma unroll
        for (int w2 = 0; w2 < K2_WPB; ++w2) s += red[w2][o];
        outp[o] = s;
    }
    if (threadIdx.x < HEADS) {
        float s = 0.f;
#pragma unroll
        for (int w2 = 0; w2 < K2_WPB; ++w2) s += redd[w2][threadIdx.x];
        outp[HEADS * CODE_DIM + threadIdx.x] = s;
    }
}

// K3: reduce per-block partials -> s[h][:] (normalized); agg[h] = s @ W[h] + b[h] -> mho
__global__ void k3_agg(const float* __restrict__ part, const float* __restrict__ W,
                       const float* __restrict__ b, float* __restrict__ out) {
    const int h   = blockIdx.x;     // 4 blocks
    const int tid = threadIdx.x;    // 256 threads

    // reduce s_un over 256 block-partials (col = tid)
    float sacc = 0.f;
    const float* p = part + h * CODE_DIM + tid;
#pragma unroll 8
    for (int bb = 0; bb < K2_BLOCKS; ++bb) sacc += p[(size_t)bb * PART_STRIDE];

    // reduce denom (tid indexes the 256 blocks)
    float dd = part[(size_t)tid * PART_STRIDE + HEADS * CODE_DIM + h];
#pragma unroll
    for (int off = 32; off; off >>= 1) dd += __shfl_xor(dd, off, 64);
    __shared__ float wred[4];
    __shared__ float den_sh;
    if ((tid & 63) == 0) wred[tid >> 6] = dd;
    __syncthreads();
    if (tid == 0) den_sh = wred[0] + wred[1] + wred[2] + wred[3];
    __syncthreads();

    __shared__ float s_sh[CODE_DIM];
    s_sh[tid] = sacc / den_sh;
    __syncthreads();

    // gemv: y[k] = sum_d s[d] * W[h][d][k] + b[h][k]; split d-range over 2 halves
    const int k    = tid & (HIDDEN - 1);
    const int half = tid >> 7;
    float y = 0.f;
    const float* wp = W + ((size_t)h * CODE_DIM + half * 128) * HIDDEN + k;
#pragma unroll 8
    for (int d = 0; d < 128; ++d) y += s_sh[half * 128 + d] * wp[(size_t)d * HIDDEN];
    __shared__ float ysh[HIDDEN];
    if (half == 1) ysh[k] = y;
    __syncthreads();
    if (half == 0)
        out[N_SPEC + h * HIDDEN + k] = y + ysh[k] + b[h * HIDDEN + k];
}

// K4: specialty_logits[i] = dot(Wc[i,:], mho) + bc[i]; one wave per logit
__global__ void k4_logits(const float* __restrict__ Wc, const float* __restrict__ bc,
                          float* __restrict__ out) {
    const int lane = threadIdx.x & 63;
    const int wv   = threadIdx.x >> 6;
    const int i    = blockIdx.x * 4 + wv;   // 64 blocks * 4 waves = 256 logits
    const float4* wr  = (const float4*)(Wc + (size_t)i * (HEADS * HIDDEN));
    const float4* mh4 = (const float4*)(out + N_SPEC);
    float4 wa = wr[lane],      ma = mh4[lane];
    float4 wb = wr[64 + lane], mb = mh4[64 + lane];
    float pp = wa.x * ma.x + wa.y * ma.y + wa.z * ma.z + wa.w * ma.w
             + wb.x * mb.x + wb.y * mb.y + wb.z * mb.z + wb.w * mb.w;
#pragma unroll
    for (int off = 32; off; off >>= 1) pp += __shfl_xor(pp, off, 64);
    if (lane == 0) out[i] = pp + bc[i];
}

extern "C" void kernel_launch(void* const* d_in, const int* in_sizes, int n_in,
                              void* d_out, int out_size, void* d_ws, size_t ws_size,
                              hipStream_t stream) {
    const float* pe   = (const float*)d_in[0];
    const float* code = (const float*)d_in[1];
    const float* W    = (const float*)d_in[2];
    const float* b    = (const float*)d_in[3];
    const float* a    = (const float*)d_in[4];
    const float* Wc   = (const float*)d_in[5];
    const float* bc   = (const float*)d_in[6];
    float* out = (float*)d_out;
    float* ws  = (float*)d_ws;

    k1_prep<<<HEADS, 256, 0, stream>>>(pe, W, b, a, ws);
    k2_main<<<K2_BLOCKS, K2_TPB, 0, stream>>>(code, ws, ws + WS_PART);
    k3_agg<<<HEADS, 256, 0, stream>>>(ws + WS_PART, W, b, out);
    k4_logits<<<64, 256, 0, stream>>>(Wc, bc, out);
}

// Round 2
// 177.933 us; speedup vs baseline: 1.1824x; 1.1824x over previous
//
#include <hip/hip_runtime.h>
#include <hip/hip_bf16.h>

#define CODE_DIM 256
#define HIDDEN   128
#define HEADS    4
#define N_CODES  100000
#define N_SPEC   256

// ---- k2 config ----
#define K2_BLOCKS 1024
#define K2_TPB    256
#define K2_WPB    4                       // waves per block
#define K2_WAVES  (K2_BLOCKS * K2_WPB)    // 4096
#define WROWS     8                       // rows per wave-tile
#define NTILES    (N_CODES / WROWS)       // 12500 exact, no tail
#define RSTRIDE   260                     // padded LDS row stride (floats): 1040 B, bank-flat
#define NSLOTS    64

// ---- ws layout (floats) ----
#define WS_V       0                       // v[h][d] : 1024
#define WS_CP      1024                    // c partials: c_part[h*4+dq] : 16
#define WS_SLOT    1040                    // 64 slots x 1028
#define SLOT_STRIDE 1028

// ---- k2 LDS layout (floats) ----
#define LDS_VSH   0                        // 1024
#define LDS_TSH   1024                     // 4 waves x 8 rows x 4 heads = 128
#define LDS_TILE  1152                     // 4 waves x 8 x 260 = 8320
#define LDS_TOTAL (LDS_TILE + K2_WPB * WROWS * RSTRIDE)   // 9472 floats = 37888 B

// s_waitcnt immediates (gfx9 encoding: vm[3:0], exp[6:4], lgkm[11:8], vm[5:4]@[15:14])
#define WAITCNT_VM0   0x0F70   // vmcnt=0,  lgkm=nowait
#define WAITCNT_LGKM0 0xC07F   // lgkm=0,   vmcnt=nowait

typedef __attribute__((address_space(1))) const void* as1cv;
typedef __attribute__((address_space(3))) void*       as3v;

// K1 (16 blocks): v[h,d] = W[h,d,:]·a2[h];  c_part = pe·(W·a1) + b·(a1+a2); zero slots.
__global__ void k1_prep(const float* __restrict__ pe, const float* __restrict__ W,
                        const float* __restrict__ b, const float* __restrict__ a,
                        float* __restrict__ ws) {
    const int bx = blockIdx.x;          // 16: (h, d-quarter)
    const int h = bx >> 2, dq = bx & 3;
    const int tid = threadIdx.x;
    const int dl = tid >> 2, q = tid & 3;   // 64 d-values x 4 k-chunks
    const int d = dq * 64 + dl;
    __shared__ float a_sh[2 * HIDDEN];
    __shared__ float cred[4];
    a_sh[tid] = a[h * 2 * HIDDEN + tid];
    __syncthreads();

    const float4* wr = (const float4*)(W + ((size_t)(h * CODE_DIM + d)) * HIDDEN + q * 32);
    float u = 0.f, v = 0.f;
#pragma unroll
    for (int j = 0; j < 8; ++j) {
        float4 wv = wr[j];
        int k = q * 32 + j * 4;
        u += wv.x * a_sh[k]     + wv.y * a_sh[k + 1]
           + wv.z * a_sh[k + 2] + wv.w * a_sh[k + 3];
        v += wv.x * a_sh[HIDDEN + k]     + wv.y * a_sh[HIDDEN + k + 1]
           + wv.z * a_sh[HIDDEN + k + 2] + wv.w * a_sh[HIDDEN + k + 3];
    }
    u += __shfl_xor(u, 1, 64); u += __shfl_xor(u, 2, 64);
    v += __shfl_xor(v, 1, 64); v += __shfl_xor(v, 2, 64);
    if (q == 0) ws[WS_V + h * CODE_DIM + d] = v;

    float cp = (q == 0) ? pe[d] * u : 0.f;
    if (dq == 0 && tid < HIDDEN) cp += b[h * HIDDEN + tid] * (a_sh[tid] + a_sh[HIDDEN + tid]);
#pragma unroll
    for (int off = 32; off; off >>= 1) cp += __shfl_xor(cp, off, 64);
    if ((tid & 63) == 0) cred[tid >> 6] = cp;
    __syncthreads();
    if (tid == 0) ws[WS_CP + h * 4 + dq] = cred[0] + cred[1] + cred[2] + cred[3];

    // zero the atomic slots (k2 depends on stream order)
    float4* z = (float4*)(ws + WS_SLOT);
    const int g = bx * 256 + tid;
#pragma unroll
    for (int i = 0; i < 5; ++i) {
        int idx = g + i * 4096;
        if (idx < (NSLOTS * SLOT_STRIDE) / 4) z[idx] = make_float4(0.f, 0.f, 0.f, 0.f);
    }
}

// K2: streamed pass over code_embs with wave-private LDS tiles (no hot-loop barriers).
__global__ __launch_bounds__(K2_TPB, 4) void k2_main(const float* __restrict__ code,
                                                     float* __restrict__ ws) {
    __shared__ float lds[LDS_TOTAL];
    const int tid  = threadIdx.x;
    const int lane = tid & 63;
    const int w    = tid >> 6;
    const int row  = lane >> 3;       // 8 rows per wave-tile
    const int seg  = lane & 7;        // 8 lanes per row, 32 cols each
    const int bx   = blockIdx.x;

    // stage v into LDS (block-shared, read-only afterwards)
    {
        float4 vv = ((const float4*)(ws + WS_V))[tid];
        *(float4*)&lds[LDS_VSH + tid * 4] = vv;
    }
    float ch[HEADS];
#pragma unroll
    for (int h = 0; h < HEADS; ++h) {
        float4 cc = *(const float4*)(ws + WS_CP + 4 * h);
        ch[h] = cc.x + cc.y + cc.z + cc.w;
    }
    __syncthreads();

    const int tilebase = LDS_TILE + w * (WROWS * RSTRIDE);
    const int xb = tilebase + row * RSTRIDE + seg * 32;

    float4 acc0 = make_float4(0,0,0,0), acc1 = acc0, acc2 = acc0, acc3 = acc0;
    float ds0 = 0.f, ds1 = 0.f, ds2 = 0.f, ds3 = 0.f;

    for (int tile = bx * K2_WPB + w; tile < NTILES; tile += K2_WAVES) {
        // ensure prior phase-2 LDS reads retired before DMA overwrites the tile
        __builtin_amdgcn_s_waitcnt(WAITCNT_LGKM0);
        const float* gbase = code + (size_t)tile * (WROWS * CODE_DIM) + lane * 4;
#pragma unroll
        for (int r = 0; r < WROWS; ++r) {
            __builtin_amdgcn_global_load_lds((as1cv)(gbase + r * CODE_DIM),
                                             (as3v)&lds[tilebase + r * RSTRIDE], 16, 0, 0);
        }
        __builtin_amdgcn_s_waitcnt(WAITCNT_VM0);

        // phase 1: per-lane partial dots over 32 cols of own row, 3-level butterfly
        float p0 = 0.f, p1 = 0.f, p2 = 0.f, p3 = 0.f;
#pragma unroll
        for (int c = 0; c < 8; ++c) {
            float4 x4 = *(const float4*)&lds[xb + c * 4];
            float4 va = *(const float4*)&lds[LDS_VSH +   0 + seg * 32 + c * 4];
            float4 vb = *(const float4*)&lds[LDS_VSH + 256 + seg * 32 + c * 4];
            float4 vc = *(const float4*)&lds[LDS_VSH + 512 + seg * 32 + c * 4];
            float4 vd = *(const float4*)&lds[LDS_VSH + 768 + seg * 32 + c * 4];
            p0 += x4.x * va.x + x4.y * va.y + x4.z * va.z + x4.w * va.w;
            p1 += x4.x * vb.x + x4.y * vb.y + x4.z * vb.z + x4.w * vb.w;
            p2 += x4.x * vc.x + x4.y * vc.y + x4.z * vc.z + x4.w * vc.w;
            p3 += x4.x * vd.x + x4.y * vd.y + x4.z * vd.z + x4.w * vd.w;
        }
#pragma unroll
        for (int off = 1; off < 8; off <<= 1) {
            p0 += __shfl_xor(p0, off, 64);
            p1 += __shfl_xor(p1, off, 64);
            p2 += __shfl_xor(p2, off, 64);
            p3 += __shfl_xor(p3, off, 64);
        }
        float e0 = p0 + ch[0]; e0 = (e0 >= 0.f) ? e0 : 0.2f * e0; float t0 = __expf(e0);
        float e1 = p1 + ch[1]; e1 = (e1 >= 0.f) ? e1 : 0.2f * e1; float t1 = __expf(e1);
        float e2 = p2 + ch[2]; e2 = (e2 >= 0.f) ? e2 : 0.2f * e2; float t2 = __expf(e2);
        float e3 = p3 + ch[3]; e3 = (e3 >= 0.f) ? e3 : 0.2f * e3; float t3 = __expf(e3);
        ds0 += t0; ds1 += t1; ds2 += t2; ds3 += t3;   // 8x redundant, scaled at write-out
        if (seg == 0) *(float4*)&lds[LDS_TSH + w * 32 + row * 4] = make_float4(t0, t1, t2, t3);
        __builtin_amdgcn_s_waitcnt(WAITCNT_LGKM0);     // t_sh visible to whole wave

        // phase 2: broadcast row + t, accumulate weighted sum (lane owns cols 4l..4l+3)
#pragma unroll
        for (int r = 0; r < WROWS; ++r) {
            float4 tr = *(const float4*)&lds[LDS_TSH + w * 32 + r * 4];
            float4 x4 = *(const float4*)&lds[tilebase + r * RSTRIDE + lane * 4];
            acc0.x += tr.x * x4.x; acc0.y += tr.x * x4.y; acc0.z += tr.x * x4.z; acc0.w += tr.x * x4.w;
            acc1.x += tr.y * x4.x; acc1.y += tr.y * x4.y; acc1.z += tr.y * x4.z; acc1.w += tr.y * x4.w;
            acc2.x += tr.z * x4.x; acc2.y += tr.z * x4.y; acc2.z += tr.z * x4.z; acc2.w += tr.z * x4.w;
            acc3.x += tr.w * x4.x; acc3.y += tr.w * x4.y; acc3.z += tr.w * x4.z; acc3.w += tr.w * x4.w;
        }
    }

    // block-level reduction (reuse LDS), then one atomic slot-add per block
    __syncthreads();
    *(float4*)&lds[w * 1024 +   0 + 4 * lane] = acc0;
    *(float4*)&lds[w * 1024 + 256 + 4 * lane] = acc1;
    *(float4*)&lds[w * 1024 + 512 + 4 * lane] = acc2;
    *(float4*)&lds[w * 1024 + 768 + 4 * lane] = acc3;
    *(float4*)&lds[4096 + (w * 64 + lane) * 4] = make_float4(ds0, ds1, ds2, ds3);
    __syncthreads();

    float* slot = ws + WS_SLOT + (size_t)(bx & (NSLOTS - 1)) * SLOT_STRIDE;
    for (int o = tid; o < HEADS * CODE_DIM; o += K2_TPB) {
        float s = lds[o] + lds[1024 + o] + lds[2048 + o] + lds[3072 + o];
        atomicAdd(slot + o, s);
    }
    {
        const int h = tid >> 6, l2 = tid & 63;
        float dv = lds[4096 +   0 + l2 * 4 + h] + lds[4096 + 256 + l2 * 4 + h]
                 + lds[4096 + 512 + l2 * 4 + h] + lds[4096 + 768 + l2 * 4 + h];
#pragma unroll
        for (int off = 32; off; off >>= 1) dv += __shfl_xor(dv, off, 64);
        if (l2 == 0) atomicAdd(slot + HEADS * CODE_DIM + h, dv * 0.125f);
    }
}

// K3 (16 blocks): reduce slots -> s[h][:]; normalize; GEMV agg = s@W + b -> mho
__global__ void k3_agg(const float* __restrict__ W, const float* __restrict__ b,
                       const float* __restrict__ ws, float* __restrict__ out) {
    const int bx = blockIdx.x;      // (h, k-quarter)
    const int h = bx >> 2, q = bx & 3;
    const int tid = threadIdx.x;
    __shared__ float s_sh[CODE_DIM];
    __shared__ float yred[8 * 32];
    __shared__ float den_sh;
    const float* slots = ws + WS_SLOT;

    if (tid < 64) {
        float dv = slots[(size_t)tid * SLOT_STRIDE + HEADS * CODE_DIM + h];
#pragma unroll
        for (int off = 32; off; off >>= 1) dv += __shfl_xor(dv, off, 64);
        if (tid == 0) den_sh = dv;
    }
    float su = 0.f;
#pragma unroll 8
    for (int s2 = 0; s2 < NSLOTS; ++s2)
        su += slots[(size_t)s2 * SLOT_STRIDE + h * CODE_DIM + tid];
    __syncthreads();
    s_sh[tid] = su / den_sh;
    __syncthreads();

    const int c = tid >> 5, kl = tid & 31;
    float y = 0.f;
    const float* wp = W + ((size_t)(h * CODE_DIM + c * 32)) * HIDDEN + q * 32 + kl;
#pragma unroll 8
    for (int d = 0; d < 32; ++d) y += s_sh[c * 32 + d] * wp[(size_t)d * HIDDEN];
    yred[c * 32 + kl] = y;
    __syncthreads();
    if (tid < 32) {
        float t = 0.f;
#pragma unroll
        for (int cc = 0; cc < 8; ++cc) t += yred[cc * 32 + tid];
        out[N_SPEC + h * HIDDEN + q * 32 + tid] = t + b[h * HIDDEN + q * 32 + tid];
    }
}

// K4: specialty_logits = Wc @ mho + bc; one wave per logit
__global__ void k4_logits(const float* __restrict__ Wc, const float* __restrict__ bc,
                          float* __restrict__ out) {
    const int lane = threadIdx.x & 63;
    const int wv   = threadIdx.x >> 6;
    const int i    = blockIdx.x * 4 + wv;
    const float4* wr  = (const float4*)(Wc + (size_t)i * (HEADS * HIDDEN));
    const float4* mh4 = (const float4*)(out + N_SPEC);
    float4 wa = wr[lane],      ma = mh4[lane];
    float4 wb = wr[64 + lane], mb = mh4[64 + lane];
    float pp = wa.x * ma.x + wa.y * ma.y + wa.z * ma.z + wa.w * ma.w
             + wb.x * mb.x + wb.y * mb.y + wb.z * mb.z + wb.w * mb.w;
#pragma unroll
    for (int off = 32; off; off >>= 1) pp += __shfl_xor(pp, off, 64);
    if (lane == 0) out[i] = pp + bc[i];
}

extern "C" void kernel_launch(void* const* d_in, const int* in_sizes, int n_in,
                              void* d_out, int out_size, void* d_ws, size_t ws_size,
                              hipStream_t stream) {
    const float* pe   = (const float*)d_in[0];
    const float* code = (const float*)d_in[1];
    const float* W    = (const float*)d_in[2];
    const float* b    = (const float*)d_in[3];
    const float* a    = (const float*)d_in[4];
    const float* Wc   = (const float*)d_in[5];
    const float* bc   = (const float*)d_in[6];
    float* out = (float*)d_out;
    float* ws  = (float*)d_ws;

    k1_prep<<<16, 256, 0, stream>>>(pe, W, b, a, ws);
    k2_main<<<K2_BLOCKS, K2_TPB, 0, stream>>>(code, ws);
    k3_agg<<<16, 256, 0, stream>>>(W, b, ws, out);
    k4_logits<<<64, 256, 0, stream>>>(Wc, bc, out);
}